// Round 10
// baseline (327.646 us; speedup 1.0000x reference)
//
#include <hip/hip_runtime.h>
#include <hip/hip_bf16.h>
#include <math.h>

typedef __attribute__((ext_vector_type(8))) short short8;
typedef __attribute__((ext_vector_type(4))) float f32x4;
typedef __attribute__((ext_vector_type(4))) unsigned int u32x4;

#define KDIM 150528
#define NT_TILES 10
#define KCHUNKS 24
#define STEPS 196         // 6272 / 32
#define BK 32
#define HDIM 1280
#define MDIM 256
#define PSTRIDE (MDIM * HDIM)
#define ABB 16384         // A: 256 rows * 64 B bf16
#define BUFB 24576        // + B: 128 rows * 64 B
// LDS: 2 buffers * 24 KB = 48 KB

// packed fp32x2 -> bf16x2 RNE, single HW instruction (no builtin on gfx950)
__device__ __forceinline__ unsigned int pk2(float a, float b) {
  unsigned int r;
  asm("v_cvt_pk_bf16_f32 %0, %1, %2" : "=v"(r) : "v"(a), "v"(b));
  return r;
}
__device__ __forceinline__ u32x4 pk8(f32x4 a, f32x4 b) {
  return (u32x4){pk2(a.x, a.y), pk2(a.z, a.w), pk2(b.x, b.y), pk2(b.z, b.w)};
}

// ---------------------------------------------------------------------------
// K1: split-K GEMM  P[kc][m][n] += X[m,k]*W[n,k] over k-chunk kc.
// Tile 256x128, BK=32, 512 thr (8 waves 4m x 2n, wave tile 64x64, acc 4x4).
// bf16 LDS (convert-once at stage): 88 KB LDS traffic/step vs R9's 176 KB.
// 64B-row swizzle slot' = slot ^ ((row>>1)&3): frag reads 2-way (free),
// stage writes conflict-free (bank-enumerated).
// R9's counted discipline kept: depth-2 named reg sets, raw s_barrier,
// lgkmcnt(0) only — vmcnt NEVER drains to 0 in the loop.
// ---------------------------------------------------------------------------
__global__ __launch_bounds__(512, 2) void k_gemm(
    const float* __restrict__ X, const float* __restrict__ W,
    float* __restrict__ P) {
  extern __shared__ char smem[];
  // XCD-chunked swizzle (240 % 8 == 0): each XCD owns 3 kc x 10 nt blocks
  const int swz = (blockIdx.x & 7) * 30 + (blockIdx.x >> 3);
  const int kc = swz / 10;
  const int nt = swz % 10;
  const long k0 = (long)kc * (BK * STEPS);

  const int tid = threadIdx.x;
  const int lane = tid & 63;
  const int wv = tid >> 6;                  // 0..7 -> 4m x 2n wave grid
  const int wm = wv >> 1, wn = wv & 1;
  const int frow = lane & 15;
  const int fslot = lane >> 4;              // k-subgroup (8 bf16)

  // staging: thread covers A rows r0,r0+128 and B row r0, slot s (8 fp32)
  const int r0 = tid >> 2;                  // 0..127
  const int s = tid & 3;
  const float* xA0 = X + (long)r0 * KDIM + k0 + s * 8;
  const float* xA1 = X + (long)(r0 + 128) * KDIM + k0 + s * 8;
  const float* wB0 = W + (long)(nt * 128 + r0) * KDIM + k0 + s * 8;
  const int ssw = (s ^ ((r0 >> 1) & 3)) << 4;      // same for r0 and r0+128
  const int aoff0 = r0 * 64 + ssw;
  const int aoff1 = (r0 + 128) * 64 + ssw;
  const int boff = ABB + r0 * 64 + ssw;

  f32x4 acc[4][4];
#pragma unroll
  for (int i = 0; i < 4; ++i)
#pragma unroll
    for (int j = 0; j < 4; ++j) acc[i][j] = (f32x4){0.f, 0.f, 0.f, 0.f};

  f32x4 A0a, A0b, A1a, A1b, B0a, B0b;   // set A (6 x f32x4)
  f32x4 C0a, C0b, C1a, C1b, D0a, D0b;   // set B

#define LOADS(p0, p1, p2, p3, p4, p5, t)                                      \
  {                                                                           \
    const long off = (long)(t)*BK;                                            \
    p0 = *(const f32x4*)(xA0 + off);                                          \
    p1 = *(const f32x4*)(xA0 + off + 4);                                      \
    p2 = *(const f32x4*)(xA1 + off);                                          \
    p3 = *(const f32x4*)(xA1 + off + 4);                                      \
    p4 = __builtin_nontemporal_load((const f32x4*)(wB0 + off));               \
    p5 = __builtin_nontemporal_load((const f32x4*)(wB0 + off + 4));           \
  }
#define CVTWRITE(buf, p0, p1, p2, p3, p4, p5)                                 \
  {                                                                           \
    *(u32x4*)((buf) + aoff0) = pk8(p0, p1);                                   \
    *(u32x4*)((buf) + aoff1) = pk8(p2, p3);                                   \
    *(u32x4*)((buf) + boff) = pk8(p4, p5);                                    \
  }
#define COMPUTE(buf)                                                          \
  {                                                                           \
    const char* L_ = (buf);                                                   \
    short8 fa[4], fb[4];                                                      \
    _Pragma("unroll") for (int i = 0; i < 4; ++i) {                           \
      const int R = wm * 64 + i * 16 + frow;                                  \
      fa[i] = *(const short8*)(L_ + R * 64 + ((fslot ^ ((R >> 1) & 3)) << 4)); \
    }                                                                         \
    _Pragma("unroll") for (int j = 0; j < 4; ++j) {                           \
      const int R = wn * 64 + j * 16 + frow;                                  \
      fb[j] = *(const short8*)(L_ + ABB + R * 64 +                            \
                               ((fslot ^ ((R >> 1) & 3)) << 4));              \
    }                                                                         \
    _Pragma("unroll") for (int i = 0; i < 4; ++i)                             \
        _Pragma("unroll") for (int j = 0; j < 4; ++j)                         \
            acc[i][j] = __builtin_amdgcn_mfma_f32_16x16x32_bf16(              \
                fa[i], fb[j], acc[i][j], 0, 0, 0);                            \
  }
#define STEPBAR()                                                             \
  asm volatile("s_waitcnt lgkmcnt(0)" ::: "memory");                          \
  __builtin_amdgcn_s_barrier();                                               \
  __builtin_amdgcn_sched_barrier(0);

  char* buf0 = smem;
  char* buf1 = smem + BUFB;

  // prologue: sets hold steps 0,1; stage 0 into buf0; reload setA with 2
  LOADS(A0a, A0b, A1a, A1b, B0a, B0b, 0);
  LOADS(C0a, C0b, C1a, C1b, D0a, D0b, 1);
  CVTWRITE(buf0, A0a, A0b, A1a, A1b, B0a, B0b);
  LOADS(A0a, A0b, A1a, A1b, B0a, B0b, 2);
  STEPBAR();

  for (int t = 0; t < STEPS; t += 2) {
    // even step t: stage t+1 (setB), reload setB <- t+3, compute buf[t]
    CVTWRITE(buf1, C0a, C0b, C1a, C1b, D0a, D0b);
    if (t + 3 < STEPS) LOADS(C0a, C0b, C1a, C1b, D0a, D0b, t + 3);
    __builtin_amdgcn_sched_barrier(0);
    COMPUTE(buf0);
    STEPBAR();
    // odd step t+1: stage t+2 (setA), reload setA <- t+4, compute buf[t+1]
    if (t + 2 < STEPS) {
      CVTWRITE(buf0, A0a, A0b, A1a, A1b, B0a, B0b);
      if (t + 4 < STEPS) LOADS(A0a, A0b, A1a, A1b, B0a, B0b, t + 4);
    }
    __builtin_amdgcn_sched_barrier(0);
    COMPUTE(buf1);
    STEPBAR();
  }

#undef LOADS
#undef CVTWRITE
#undef COMPUTE
#undef STEPBAR

  // C/D layout: col=lane&15, row=(lane>>4)*4+r  [m89]
  float* Pc = P + (long)kc * PSTRIDE + nt * 128;
  const int rb = wm * 64 + ((lane >> 4) << 2);
  const int cb = wn * 64 + frow;
#pragma unroll
  for (int i = 0; i < 4; ++i)
#pragma unroll
    for (int j = 0; j < 4; ++j) {
      const int col = cb + j * 16;
#pragma unroll
      for (int r = 0; r < 4; ++r)
        Pc[(long)(rb + i * 16 + r) * HDIM + col] = acc[i][j][r];
    }
}

// ---------------------------------------------------------------------------
// K2: S4D kernel table, one thread per (h,l).
// ---------------------------------------------------------------------------
__global__ __launch_bounds__(256) void k_s4d(
    const float* __restrict__ log_dt, const float* __restrict__ lar,
    const float* __restrict__ C, float* __restrict__ ktab) {
  const int idx = blockIdx.x * 256 + threadIdx.x;  // 1280*64
  const int h = idx >> 6, l = idx & 63;
  const float dt = expf(log_dt[h]);
  const float fl = (float)l;
  float acc = 0.f;
#pragma unroll 4
  for (int n = 0; n < 32; ++n) {
    const float A = -expf(lar[h * 32 + n]);
    const float dtA = A * dt;
    const float Cb = C[h * 32 + n] * expm1f(dtA) / A;
    acc += Cb * expf(dtA * fl);
  }
  ktab[idx] = 2.f * acc;
}

// ---------------------------------------------------------------------------
// K3: split-K reduce  U[m][h] = bb[h] + sum_kc P  (full-chip parallel)
// ---------------------------------------------------------------------------
__global__ __launch_bounds__(256) void k_red(
    const float* __restrict__ P, const float* __restrict__ bb,
    float* __restrict__ U) {
  const int idx = blockIdx.x * 256 + threadIdx.x;  // 256*1280
  float s = bb[idx % HDIM];
#pragma unroll
  for (int c = 0; c < KCHUNKS; ++c) s += P[(long)c * PSTRIDE + idx];
  U[idx] = s;
}

// ---------------------------------------------------------------------------
// K4: causal conv at l=63 + D skip + exact GELU (reads tiny U)
// ---------------------------------------------------------------------------
__global__ __launch_bounds__(256) void k_conv(
    const float* __restrict__ U, const float* __restrict__ ktab,
    const float* __restrict__ Dv, float* __restrict__ y63) {
  __shared__ float kt[64 * 65];
  const int t = threadIdx.x;
  const int hw = blockIdx.x * 64;
  for (int i = t; i < 4096; i += 256)
    kt[(i >> 6) * 65 + (i & 63)] = ktab[(hw + (i >> 6)) * 64 + (i & 63)];
  __syncthreads();
  const int hl = t & 63, b = t >> 6;
  const int h = hw + hl;
  float y = 0.f;
  for (int m = 0; m < 64; ++m)
    y += U[(long)(b * 64 + m) * HDIM + h] * kt[hl * 65 + (63 - m)];
  y += Dv[h] * U[(long)(b * 64 + 63) * HDIM + h];
  y63[b * HDIM + h] = 0.5f * y * (1.f + erff(y * 0.70710678118654752f));
}

// ---------------------------------------------------------------------------
// K5: gating z=Wc@y63+bc, last = a*sigmoid(g). One wave per h-row.
// ---------------------------------------------------------------------------
__global__ __launch_bounds__(64) void k_gate(
    const float* __restrict__ y63, const float* __restrict__ Wc,
    const float* __restrict__ bc, float* __restrict__ lastv) {
  const int r = blockIdx.x;       // 0..1279
  const int l = threadIdx.x;      // 0..63
  const float* wa = Wc + (long)r * HDIM;
  const float* wg = Wc + (long)(HDIM + r) * HDIM;
  float sa[4] = {0.f, 0.f, 0.f, 0.f}, sg[4] = {0.f, 0.f, 0.f, 0.f};
#pragma unroll
  for (int seg = 0; seg < 5; ++seg) {
    const int j = seg * 256 + l * 4;
    const f32x4 a4 = *(const f32x4*)(wa + j);
    const f32x4 g4 = *(const f32x4*)(wg + j);
#pragma unroll
    for (int b = 0; b < 4; ++b) {
      const f32x4 yv = *(const f32x4*)(y63 + b * HDIM + j);
      sa[b] += a4.x * yv.x + a4.y * yv.y + a4.z * yv.z + a4.w * yv.w;
      sg[b] += g4.x * yv.x + g4.y * yv.y + g4.z * yv.z + g4.w * yv.w;
    }
  }
#pragma unroll
  for (int off = 32; off; off >>= 1)
#pragma unroll
    for (int b = 0; b < 4; ++b) {
      sa[b] += __shfl_down(sa[b], off);
      sg[b] += __shfl_down(sg[b], off);
    }
  if (l == 0) {
    const float ba = bc[r], bg = bc[HDIM + r];
#pragma unroll
    for (int b = 0; b < 4; ++b) {
      const float za = ba + sa[b], zg = bg + sg[b];
      lastv[b * HDIM + r] = za / (1.f + expf(-zg));
    }
  }
}

// ---------------------------------------------------------------------------
// K6: head  h1 = relu(last @ W1^T + b1); out = h1 @ W2^T + b2
// ---------------------------------------------------------------------------
__global__ __launch_bounds__(64) void k_head(
    const float* __restrict__ lastv, const float* __restrict__ W1,
    const float* __restrict__ b1, const float* __restrict__ W2,
    const float* __restrict__ b2, float* __restrict__ out) {
  __shared__ float ll[HDIM];
  __shared__ float h1[64];
  const int b = blockIdx.x, t = threadIdx.x;
  for (int i = t; i < HDIM; i += 64) ll[i] = lastv[b * HDIM + i];
  __syncthreads();
  {
    const float* w = W1 + t * HDIM;
    float s = b1[t];
    for (int j = 0; j < HDIM; j += 4) {
      const f32x4 wv = *(const f32x4*)(w + j);
      s += wv.x * ll[j] + wv.y * ll[j + 1] + wv.z * ll[j + 2] + wv.w * ll[j + 3];
    }
    h1[t] = fmaxf(s, 0.f);
  }
  __syncthreads();
  if (t < 60) {
    const float* w = W2 + t * 64;
    float o = b2[t];
#pragma unroll
    for (int r = 0; r < 64; ++r) o += w[r] * h1[r];
    out[b * 60 + t] = o;
  }
}

extern "C" void kernel_launch(void* const* d_in, const int* in_sizes, int n_in,
                              void* d_out, int out_size, void* d_ws, size_t ws_size,
                              hipStream_t stream) {
  const float* x   = (const float*)d_in[0];
  const float* Wb  = (const float*)d_in[1];
  const float* bb  = (const float*)d_in[2];
  const float* ldt = (const float*)d_in[3];
  const float* C   = (const float*)d_in[4];
  const float* lar = (const float*)d_in[5];
  const float* Dv  = (const float*)d_in[6];
  const float* Wc  = (const float*)d_in[7];
  const float* bc  = (const float*)d_in[8];
  const float* W1  = (const float*)d_in[9];
  const float* b1  = (const float*)d_in[10];
  const float* W2  = (const float*)d_in[11];
  const float* b2  = (const float*)d_in[12];
  float* out = (float*)d_out;

  float* P     = (float*)d_ws;                     // 24*256*1280 f32 = 31.5 MB
  float* ktab  = P + (long)KCHUNKS * PSTRIDE;      // 1280*64
  float* U     = ktab + HDIM * 64;                 // 256*1280
  float* y63   = U + PSTRIDE;                      // 4*1280
  float* lastv = y63 + 4 * HDIM;                   // 4*1280

  (void)hipFuncSetAttribute(reinterpret_cast<const void*>(k_gemm),
                            hipFuncAttributeMaxDynamicSharedMemorySize,
                            2 * BUFB);

  k_s4d<<<320, 256, 0, stream>>>(ldt, lar, C, ktab);
  k_gemm<<<NT_TILES * KCHUNKS, 512, 2 * BUFB, stream>>>(x, Wb, P);
  k_red<<<PSTRIDE / 256, 256, 0, stream>>>(P, bb, U);
  k_conv<<<20, 256, 0, stream>>>(U, ktab, Dv, y63);
  k_gate<<<HDIM, 64, 0, stream>>>(y63, Wc, bc, lastv);
  k_head<<<4, 64, 0, stream>>>(lastv, W1, b1, W2, b2, out);
}

// Round 12
// 295.873 us; speedup vs baseline: 1.1074x; 1.1074x over previous
//
#include <hip/hip_runtime.h>
#include <hip/hip_bf16.h>
#include <math.h>

typedef __attribute__((ext_vector_type(8))) short short8;
typedef __attribute__((ext_vector_type(4))) float f32x4;
typedef __attribute__((ext_vector_type(4))) unsigned int u32x4;

#define KDIM 150528
#define KDIMB ((long)KDIM * 4)
#define NT_TILES 10
#define KCHUNKS 24
#define STEPS 196         // 6272 / 32
#define BK 32             // fp32 -> 128 B LDS rows
#define HDIM 1280
#define MDIM 256
#define PSTRIDE (MDIM * HDIM)
#define ABYTES 32768      // A: 256 rows * 128 B
#define BUFB 49152        // + B: 128 rows * 128 B
// LDS: 3 buffers * 48 KB = 144 KB -> 1 block/CU

// packed fp32x2 -> bf16x2 RNE, single HW instruction (no builtin on gfx950)
__device__ __forceinline__ unsigned int pk2(float a, float b) {
  unsigned int r;
  asm("v_cvt_pk_bf16_f32 %0, %1, %2" : "=v"(r) : "v"(a), "v"(b));
  return r;
}

// async global->LDS DMA, 16 B per lane, zero VGPR cost
__device__ __forceinline__ void gload16(const void* g, const char* l) {
  __builtin_amdgcn_global_load_lds(
      (const __attribute__((address_space(1))) unsigned int*)g,
      (__attribute__((address_space(3))) unsigned int*)l, 16, 0, 0);
}

__device__ __forceinline__ short8 cvt8(f32x4 lo, f32x4 hi) {
  union { u32x4 u; short8 s; } c;
  c.u = (u32x4){pk2(lo.x, lo.y), pk2(lo.z, lo.w), pk2(hi.x, hi.y), pk2(hi.z, hi.w)};
  return c.s;
}

// ---------------------------------------------------------------------------
// K1: split-K GEMM  P[kc][m][n] += X[m,k]*W[n,k] over k-chunk kc.
// Tile 256x128, BK=32, 512 thr (8 waves 4m x 2n, wave tile 64x64, acc 4x4).
// R9 skeleton (proven 297us): fp32 DMA staging, 3 LDS bufs, depth-2,
// counted s_waitcnt vmcnt(6) + ONE raw s_barrier per step (never drain).
// R11 tuning (fixed): explicit phase order {ds_read x16 -> STAGE issue ->
// cvt+MFMA} pinned with sched_barrier, T5 setprio(1) around MFMA cluster.
// BUGFIX vs R11: lo/hi fragment offsets each XOR'd separately —
// (cb^sw)+16 != (cb+16)^sw for odd rows (sw bit4). R11 swapped k-halves.
// ---------------------------------------------------------------------------
__global__ __launch_bounds__(512, 2) void k_gemm(
    const float* __restrict__ X, const float* __restrict__ W,
    float* __restrict__ P) {
  extern __shared__ char smem[];
  // XCD-chunked swizzle (240 % 8 == 0): each XCD owns 3 kc x 10 nt blocks
  const int swz = (blockIdx.x & 7) * 30 + (blockIdx.x >> 3);
  const int kc = swz / 10;
  const int nt = swz % 10;
  const long k0b = (long)kc * (BK * STEPS) * 4;

  const int tid = threadIdx.x;
  const int lane = tid & 63;
  const int wv = tid >> 6;                  // 0..7 -> 4m x 2n wave grid
  const int wm = wv >> 1, wn = wv & 1;
  const int frow = lane & 15;
  const int cbase = (lane >> 4) << 5;       // fp32 byte col of the 8-k group

  // staging geometry: thread covers row (q*64 + tid>>3), 16 B chunk (tid&7)
  const int srow = tid >> 3;                // 0..63
  const int perm = ((tid & 7) ^ (srow & 7)) << 4;  // inverse-swizzle source
  const char* xbase = (const char*)X + (long)srow * KDIMB + k0b + perm;
  const char* wbase = (const char*)W + (long)(nt * 128 + srow) * KDIMB + k0b + perm;

  // loop-invariant fragment byte offsets: lo and hi XOR'd SEPARATELY
  int aoffl[4], aoffh[4], boffl[4], boffh[4];
#pragma unroll
  for (int i = 0; i < 4; ++i) {
    const int Ra = wm * 64 + i * 16 + frow;
    const int swa = (Ra & 7) << 4;
    aoffl[i] = Ra * 128 + (cbase ^ swa);
    aoffh[i] = Ra * 128 + ((cbase + 16) ^ swa);
    const int Rb = wn * 64 + i * 16 + frow;
    const int swb = (Rb & 7) << 4;
    boffl[i] = ABYTES + Rb * 128 + (cbase ^ swb);
    boffh[i] = ABYTES + Rb * 128 + ((cbase + 16) ^ swb);
  }

  f32x4 acc[4][4];
#pragma unroll
  for (int i = 0; i < 4; ++i)
#pragma unroll
    for (int j = 0; j < 4; ++j) acc[i][j] = (f32x4){0.f, 0.f, 0.f, 0.f};

#define STAGE(buf, t)                                                         \
  {                                                                           \
    const long ko = (long)(t) * (BK * 4);                                     \
    _Pragma("unroll") for (int q = 0; q < 4; ++q)                             \
        gload16(xbase + (long)q * 64 * KDIMB + ko,                            \
                (buf) + q * 8192 + wv * 1024);                                \
    _Pragma("unroll") for (int q = 0; q < 2; ++q)                             \
        gload16(wbase + (long)q * 64 * KDIMB + ko,                            \
                (buf) + ABYTES + q * 8192 + wv * 1024);                       \
  }

  // phase 1: issue all 16 ds_reads (raw fp32 halves, named vars)
#define LOADFRAGS(buf)                                                        \
  f32x4 a0l = *(const f32x4*)((buf) + aoffl[0]),                              \
        a0h = *(const f32x4*)((buf) + aoffh[0]),                              \
        a1l = *(const f32x4*)((buf) + aoffl[1]),                              \
        a1h = *(const f32x4*)((buf) + aoffh[1]),                              \
        a2l = *(const f32x4*)((buf) + aoffl[2]),                              \
        a2h = *(const f32x4*)((buf) + aoffh[2]),                              \
        a3l = *(const f32x4*)((buf) + aoffl[3]),                              \
        a3h = *(const f32x4*)((buf) + aoffh[3]),                              \
        b0l = *(const f32x4*)((buf) + boffl[0]),                              \
        b0h = *(const f32x4*)((buf) + boffh[0]),                              \
        b1l = *(const f32x4*)((buf) + boffl[1]),                              \
        b1h = *(const f32x4*)((buf) + boffh[1]),                              \
        b2l = *(const f32x4*)((buf) + boffl[2]),                              \
        b2h = *(const f32x4*)((buf) + boffh[2]),                              \
        b3l = *(const f32x4*)((buf) + boffl[3]),                              \
        b3h = *(const f32x4*)((buf) + boffh[3]);

  // phase 3: convert + 16 MFMA (setprio-wrapped by caller)
#define CVTMFMA()                                                             \
  {                                                                           \
    short8 fa[4], fb[4];                                                      \
    fa[0] = cvt8(a0l, a0h); fa[1] = cvt8(a1l, a1h);                           \
    fa[2] = cvt8(a2l, a2h); fa[3] = cvt8(a3l, a3h);                           \
    fb[0] = cvt8(b0l, b0h); fb[1] = cvt8(b1l, b1h);                           \
    fb[2] = cvt8(b2l, b2h); fb[3] = cvt8(b3l, b3h);                           \
    _Pragma("unroll") for (int i = 0; i < 4; ++i)                             \
        _Pragma("unroll") for (int j = 0; j < 4; ++j)                         \
            acc[i][j] = __builtin_amdgcn_mfma_f32_16x16x32_bf16(              \
                fa[i], fb[j], acc[i][j], 0, 0, 0);                            \
  }

  char* b_cur = smem;
  char* b_nxt = smem + BUFB;
  char* b_stg = smem + 2 * BUFB;

  // prologue: steps 0 and 1 in flight (12 outstanding VMEM ops per wave)
  STAGE(b_cur, 0);
  STAGE(b_nxt, 1);

  for (int t = 0; t < STEPS - 1; ++t) {
    // counted wait: 12 outstanding -> oldest 6 (step t) landed. NOT vmcnt(0).
    asm volatile("s_waitcnt vmcnt(6)" ::: "memory");
    __builtin_amdgcn_s_barrier();           // all waves' step-t loads visible
    __builtin_amdgcn_sched_barrier(0);
    LOADFRAGS(b_cur);                       // 16x ds_read_b128 issued first
    __builtin_amdgcn_sched_barrier(0);
    if (t + 2 < STEPS) STAGE(b_stg, t + 2); // VMEM issue overlaps ds latency
    __builtin_amdgcn_sched_barrier(0);
    __builtin_amdgcn_s_setprio(1);
    CVTMFMA();                              // compiler inserts counted lgkmcnt
    __builtin_amdgcn_s_setprio(0);
    char* tmp = b_cur; b_cur = b_nxt; b_nxt = b_stg; b_stg = tmp;
  }
  // final step: drain everything
  asm volatile("s_waitcnt vmcnt(0)" ::: "memory");
  __builtin_amdgcn_s_barrier();
  __builtin_amdgcn_sched_barrier(0);
  {
    LOADFRAGS(b_cur);
    CVTMFMA();
  }

#undef STAGE
#undef LOADFRAGS
#undef CVTMFMA

  // C/D layout: col=lane&15, row=(lane>>4)*4+r  [m89]
  float* Pc = P + (long)kc * PSTRIDE + nt * 128;
  const int rb = wm * 64 + ((lane >> 4) << 2);
  const int cb = wn * 64 + frow;
#pragma unroll
  for (int i = 0; i < 4; ++i)
#pragma unroll
    for (int j = 0; j < 4; ++j) {
      const int col = cb + j * 16;
#pragma unroll
      for (int r = 0; r < 4; ++r)
        Pc[(long)(rb + i * 16 + r) * HDIM + col] = acc[i][j][r];
    }
}

// ---------------------------------------------------------------------------
// K2: S4D kernel table, one thread per (h,l).
// ---------------------------------------------------------------------------
__global__ __launch_bounds__(256) void k_s4d(
    const float* __restrict__ log_dt, const float* __restrict__ lar,
    const float* __restrict__ C, float* __restrict__ ktab) {
  const int idx = blockIdx.x * 256 + threadIdx.x;  // 1280*64
  const int h = idx >> 6, l = idx & 63;
  const float dt = expf(log_dt[h]);
  const float fl = (float)l;
  float acc = 0.f;
#pragma unroll 4
  for (int n = 0; n < 32; ++n) {
    const float A = -expf(lar[h * 32 + n]);
    const float dtA = A * dt;
    const float Cb = C[h * 32 + n] * expm1f(dtA) / A;
    acc += Cb * expf(dtA * fl);
  }
  ktab[idx] = 2.f * acc;
}

// ---------------------------------------------------------------------------
// K3: split-K reduce  U[m][h] = bb[h] + sum_kc P  (full-chip parallel)
// ---------------------------------------------------------------------------
__global__ __launch_bounds__(256) void k_red(
    const float* __restrict__ P, const float* __restrict__ bb,
    float* __restrict__ U) {
  const int idx = blockIdx.x * 256 + threadIdx.x;  // 256*1280
  float s = bb[idx % HDIM];
#pragma unroll
  for (int c = 0; c < KCHUNKS; ++c) s += P[(long)c * PSTRIDE + idx];
  U[idx] = s;
}

// ---------------------------------------------------------------------------
// K4: causal conv at l=63 + D skip + exact GELU (reads tiny U)
// ---------------------------------------------------------------------------
__global__ __launch_bounds__(256) void k_conv(
    const float* __restrict__ U, const float* __restrict__ ktab,
    const float* __restrict__ Dv, float* __restrict__ y63) {
  __shared__ float kt[64 * 65];
  const int t = threadIdx.x;
  const int hw = blockIdx.x * 64;
  for (int i = t; i < 4096; i += 256)
    kt[(i >> 6) * 65 + (i & 63)] = ktab[(hw + (i >> 6)) * 64 + (i & 63)];
  __syncthreads();
  const int hl = t & 63, b = t >> 6;
  const int h = hw + hl;
  float y = 0.f;
  for (int m = 0; m < 64; ++m)
    y += U[(long)(b * 64 + m) * HDIM + h] * kt[hl * 65 + (63 - m)];
  y += Dv[h] * U[(long)(b * 64 + 63) * HDIM + h];
  y63[b * HDIM + h] = 0.5f * y * (1.f + erff(y * 0.70710678118654752f));
}

// ---------------------------------------------------------------------------
// K5: gating z=Wc@y63+bc, last = a*sigmoid(g). One wave per h-row.
// ---------------------------------------------------------------------------
__global__ __launch_bounds__(64) void k_gate(
    const float* __restrict__ y63, const float* __restrict__ Wc,
    const float* __restrict__ bc, float* __restrict__ lastv) {
  const int r = blockIdx.x;       // 0..1279
  const int l = threadIdx.x;      // 0..63
  const float* wa = Wc + (long)r * HDIM;
  const float* wg = Wc + (long)(HDIM + r) * HDIM;
  float sa[4] = {0.f, 0.f, 0.f, 0.f}, sg[4] = {0.f, 0.f, 0.f, 0.f};
#pragma unroll
  for (int seg = 0; seg < 5; ++seg) {
    const int j = seg * 256 + l * 4;
    const f32x4 a4 = *(const f32x4*)(wa + j);
    const f32x4 g4 = *(const f32x4*)(wg + j);
#pragma unroll
    for (int b = 0; b < 4; ++b) {
      const f32x4 yv = *(const f32x4*)(y63 + b * HDIM + j);
      sa[b] += a4.x * yv.x + a4.y * yv.y + a4.z * yv.z + a4.w * yv.w;
      sg[b] += g4.x * yv.x + g4.y * yv.y + g4.z * yv.z + g4.w * yv.w;
    }
  }
#pragma unroll
  for (int off = 32; off; off >>= 1)
#pragma unroll
    for (int b = 0; b < 4; ++b) {
      sa[b] += __shfl_down(sa[b], off);
      sg[b] += __shfl_down(sg[b], off);
    }
  if (l == 0) {
    const float ba = bc[r], bg = bc[HDIM + r];
#pragma unroll
    for (int b = 0; b < 4; ++b) {
      const float za = ba + sa[b], zg = bg + sg[b];
      lastv[b * HDIM + r] = za / (1.f + expf(-zg));
    }
  }
}

// ---------------------------------------------------------------------------
// K6: head  h1 = relu(last @ W1^T + b1); out = h1 @ W2^T + b2
// ---------------------------------------------------------------------------
__global__ __launch_bounds__(64) void k_head(
    const float* __restrict__ lastv, const float* __restrict__ W1,
    const float* __restrict__ b1, const float* __restrict__ W2,
    const float* __restrict__ b2, float* __restrict__ out) {
  __shared__ float ll[HDIM];
  __shared__ float h1[64];
  const int b = blockIdx.x, t = threadIdx.x;
  for (int i = t; i < HDIM; i += 64) ll[i] = lastv[b * HDIM + i];
  __syncthreads();
  {
    const float* w = W1 + t * HDIM;
    float s = b1[t];
    for (int j = 0; j < HDIM; j += 4) {
      const f32x4 wv = *(const f32x4*)(w + j);
      s += wv.x * ll[j] + wv.y * ll[j + 1] + wv.z * ll[j + 2] + wv.w * ll[j + 3];
    }
    h1[t] = fmaxf(s, 0.f);
  }
  __syncthreads();
  if (t < 60) {
    const float* w = W2 + t * 64;
    float o = b2[t];
#pragma unroll
    for (int r = 0; r < 64; ++r) o += w[r] * h1[r];
    out[b * 60 + t] = o;
  }
}

extern "C" void kernel_launch(void* const* d_in, const int* in_sizes, int n_in,
                              void* d_out, int out_size, void* d_ws, size_t ws_size,
                              hipStream_t stream) {
  const float* x   = (const float*)d_in[0];
  const float* Wb  = (const float*)d_in[1];
  const float* bb  = (const float*)d_in[2];
  const float* ldt = (const float*)d_in[3];
  const float* C   = (const float*)d_in[4];
  const float* lar = (const float*)d_in[5];
  const float* Dv  = (const float*)d_in[6];
  const float* Wc  = (const float*)d_in[7];
  const float* bc  = (const float*)d_in[8];
  const float* W1  = (const float*)d_in[9];
  const float* b1  = (const float*)d_in[10];
  const float* W2  = (const float*)d_in[11];
  const float* b2  = (const float*)d_in[12];
  float* out = (float*)d_out;

  float* P     = (float*)d_ws;                     // 24*256*1280 f32 = 31.5 MB
  float* ktab  = P + (long)KCHUNKS * PSTRIDE;      // 1280*64
  float* U     = ktab + HDIM * 64;                 // 256*1280
  float* y63   = U + PSTRIDE;                      // 4*1280
  float* lastv = y63 + 4 * HDIM;                   // 4*1280

  (void)hipFuncSetAttribute(reinterpret_cast<const void*>(k_gemm),
                            hipFuncAttributeMaxDynamicSharedMemorySize,
                            3 * BUFB);

  k_s4d<<<320, 256, 0, stream>>>(ldt, lar, C, ktab);
  k_gemm<<<NT_TILES * KCHUNKS, 512, 3 * BUFB, stream>>>(x, Wb, P);
  k_red<<<PSTRIDE / 256, 256, 0, stream>>>(P, bb, U);
  k_conv<<<20, 256, 0, stream>>>(U, ktab, Dv, y63);
  k_gate<<<HDIM, 64, 0, stream>>>(y63, Wc, bc, lastv);
  k_head<<<4, 64, 0, stream>>>(lastv, W1, b1, W2, b2, out);
}